// Round 1
// baseline (1230.507 us; speedup 1.0000x reference)
//
#include <hip/hip_runtime.h>

#define KK 512
#define NN 512
#define DD 16
#define MM 64
#define MRF 16
#define NRF 64

typedef float4 f4;

__device__ __forceinline__ void store16(float* __restrict__ dst, const float* v) {
#pragma unroll
    for (int q = 0; q < 4; ++q) {
        reinterpret_cast<f4*>(dst)[q] = make_float4(v[4*q+0], v[4*q+1], v[4*q+2], v[4*q+3]);
    }
}

// ---------------------------------------------------------------------------
// Kernel 1: per-k prep.  temp = conjT(H)@U_RF@U_BB ; TW = temp@W ;
//           Brho = TW + 0.5*(V_RF@V_BB/rhoX - Y)
// grid = K blocks, 512 threads (one per output row n)
// ---------------------------------------------------------------------------
__global__ __launch_bounds__(512) void prep_kernel(
    const float* __restrict__ H, const float* __restrict__ U_RF,
    const float* __restrict__ U_BB, const float* __restrict__ W,
    const float* __restrict__ V_RF, const float* __restrict__ V_BB,
    const float* __restrict__ Y, const float* __restrict__ rhoX,
    float* __restrict__ temp, float* __restrict__ TW, float* __restrict__ Brho)
{
    const int k = blockIdx.x;
    const int n = threadIdx.x;

    __shared__ float sUr[MM][MRF], sUi[MM][MRF];
    __shared__ float sUBr[MRF][DD], sUBi[MRF][DD];
    __shared__ float sWr[DD][DD], sWi[DD][DD];
    __shared__ float sVBr[NRF][DD], sVBi[NRF][DD];

    {
        const float* p = U_RF + (size_t)k*2*MM*MRF;
        for (int t = n; t < MM*MRF; t += 512) { sUr[t>>4][t&15] = p[t]; sUi[t>>4][t&15] = p[MM*MRF + t]; }
        const float* q = U_BB + (size_t)k*2*MRF*DD;
        for (int t = n; t < MRF*DD; t += 512) { sUBr[t>>4][t&15] = q[t]; sUBi[t>>4][t&15] = q[MRF*DD + t]; }
        const float* w = W + (size_t)k*2*DD*DD;
        for (int t = n; t < DD*DD; t += 512) { sWr[t>>4][t&15] = w[t]; sWi[t>>4][t&15] = w[DD*DD + t]; }
        const float* v = V_BB + (size_t)k*2*NRF*DD;
        for (int t = n; t < NRF*DD; t += 512) { sVBr[t>>4][t&15] = v[t]; sVBi[t>>4][t&15] = v[NRF*DD + t]; }
    }
    __syncthreads();

    // t[r] = sum_m conj(H[m,n]) * U_RF[m,r]
    float tr[MRF], ti[MRF];
#pragma unroll
    for (int r = 0; r < MRF; ++r) { tr[r] = 0.f; ti[r] = 0.f; }
    const float* Hr = H + ((size_t)k*2+0)*MM*NN + n;
    const float* Hi = H + ((size_t)k*2+1)*MM*NN + n;
#pragma unroll 4
    for (int m = 0; m < MM; ++m) {
        float hr = Hr[(size_t)m*NN];
        float hi = Hi[(size_t)m*NN];
#pragma unroll
        for (int r = 0; r < MRF; ++r) {
            float ur = sUr[m][r], ui = sUi[m][r];
            tr[r] += hr*ur + hi*ui;
            ti[r] += hr*ui - hi*ur;
        }
    }
    // temp[d] = sum_r t[r] * U_BB[r,d]
    float tmr[DD], tmi[DD];
#pragma unroll
    for (int d = 0; d < DD; ++d) { tmr[d] = 0.f; tmi[d] = 0.f; }
#pragma unroll
    for (int r = 0; r < MRF; ++r) {
        float ar = tr[r], ai = ti[r];
#pragma unroll
        for (int d = 0; d < DD; ++d) {
            float br = sUBr[r][d], bi = sUBi[r][d];
            tmr[d] += ar*br - ai*bi;
            tmi[d] += ar*bi + ai*br;
        }
    }
    store16(temp + ((size_t)k*2+0)*NN*DD + (size_t)n*DD, tmr);
    store16(temp + ((size_t)k*2+1)*NN*DD + (size_t)n*DD, tmi);

    // TW[d] = sum_dp temp[dp] * W[dp,d]
    float twr[DD], twi[DD];
#pragma unroll
    for (int d = 0; d < DD; ++d) { twr[d] = 0.f; twi[d] = 0.f; }
#pragma unroll
    for (int dp = 0; dp < DD; ++dp) {
        float ar = tmr[dp], ai = tmi[dp];
#pragma unroll
        for (int d = 0; d < DD; ++d) {
            float br = sWr[dp][d], bi = sWi[dp][d];
            twr[d] += ar*br - ai*bi;
            twi[d] += ar*bi + ai*br;
        }
    }
    store16(TW + ((size_t)k*2+0)*NN*DD + (size_t)n*DD, twr);
    store16(TW + ((size_t)k*2+1)*NN*DD + (size_t)n*DD, twi);

    // VV[d] = sum_r V_RF[n,r] * V_BB[r,d]
    float vvr[DD], vvi[DD];
#pragma unroll
    for (int d = 0; d < DD; ++d) { vvr[d] = 0.f; vvi[d] = 0.f; }
    const float* Vr = V_RF + (size_t)0*NN*NRF + (size_t)n*NRF;
    const float* Vi = V_RF + (size_t)1*NN*NRF + (size_t)n*NRF;
#pragma unroll 4
    for (int r = 0; r < NRF; ++r) {
        float vr = Vr[r], vi = Vi[r];
#pragma unroll
        for (int d = 0; d < DD; ++d) {
            vvr[d] += vr*sVBr[r][d] - vi*sVBi[r][d];
            vvi[d] += vr*sVBi[r][d] + vi*sVBr[r][d];
        }
    }
    const float irx = 1.f / rhoX[0];
    const float* Yr = Y + ((size_t)k*2+0)*NN*DD + (size_t)n*DD;
    const float* Yi = Y + ((size_t)k*2+1)*NN*DD + (size_t)n*DD;
    float obr[DD], obi[DD];
#pragma unroll
    for (int d = 0; d < DD; ++d) {
        obr[d] = twr[d] + 0.5f*(vvr[d]*irx - Yr[d]);
        obi[d] = twi[d] + 0.5f*(vvi[d]*irx - Yi[d]);
    }
    store16(Brho + ((size_t)k*2+0)*NN*DD + (size_t)n*DD, obr);
    store16(Brho + ((size_t)k*2+1)*NN*DD + (size_t)n*DD, obi);
}

// ---------------------------------------------------------------------------
// Kernel 2: Epart[ks] = sum_{k in slice} TW_k @ temp_k^H   (complex, 512x512)
// grid (16,16,4): 32x32 output tile, split-K by 4. block 256, 2x2 per thread.
// ---------------------------------------------------------------------------
__global__ __launch_bounds__(256) void egemm_kernel(
    const float* __restrict__ TW, const float* __restrict__ temp,
    float* __restrict__ Epart)
{
    const int i0 = blockIdx.y * 32;
    const int j0 = blockIdx.x * 32;
    const int ks = blockIdx.z;
    const int tx = threadIdx.x & 15;
    const int ty = threadIdx.x >> 4;

    __shared__ float sAr[32][17], sAi[32][17];   // TW rows   [i][d]
    __shared__ float sCr[32][17], sCi[32][17];   // temp rows [j][d]

    float accr[2][2] = {{0.f,0.f},{0.f,0.f}};
    float acci[2][2] = {{0.f,0.f},{0.f,0.f}};

    const int lr = threadIdx.x >> 3;        // 0..31
    const int lc = (threadIdx.x & 7) * 2;   // 0..14

    for (int k = ks*128; k < ks*128 + 128; ++k) {
        const float* Ar = TW   + ((size_t)k*2+0)*NN*DD;
        const float* Ai = TW   + ((size_t)k*2+1)*NN*DD;
        const float* Cr = temp + ((size_t)k*2+0)*NN*DD;
        const float* Ci = temp + ((size_t)k*2+1)*NN*DD;
        float2 va = *(const float2*)(Ar + (size_t)(i0+lr)*DD + lc);
        float2 vb = *(const float2*)(Ai + (size_t)(i0+lr)*DD + lc);
        float2 vc = *(const float2*)(Cr + (size_t)(j0+lr)*DD + lc);
        float2 vd = *(const float2*)(Ci + (size_t)(j0+lr)*DD + lc);
        __syncthreads();
        sAr[lr][lc] = va.x; sAr[lr][lc+1] = va.y;
        sAi[lr][lc] = vb.x; sAi[lr][lc+1] = vb.y;
        sCr[lr][lc] = vc.x; sCr[lr][lc+1] = vc.y;
        sCi[lr][lc] = vd.x; sCi[lr][lc+1] = vd.y;
        __syncthreads();
#pragma unroll
        for (int d = 0; d < DD; ++d) {
            float ar0 = sAr[ty*2+0][d], ar1 = sAr[ty*2+1][d];
            float ai0 = sAi[ty*2+0][d], ai1 = sAi[ty*2+1][d];
            float cr0 = sCr[tx*2+0][d], cr1 = sCr[tx*2+1][d];
            float ci0 = sCi[tx*2+0][d], ci1 = sCi[tx*2+1][d];
            // (a)(conj c): re = ar*cr + ai*ci ; im = ai*cr - ar*ci
            accr[0][0] += ar0*cr0 + ai0*ci0;  acci[0][0] += ai0*cr0 - ar0*ci0;
            accr[0][1] += ar0*cr1 + ai0*ci1;  acci[0][1] += ai0*cr1 - ar0*ci1;
            accr[1][0] += ar1*cr0 + ai1*ci0;  acci[1][0] += ai1*cr0 - ar1*ci0;
            accr[1][1] += ar1*cr1 + ai1*ci1;  acci[1][1] += ai1*cr1 - ar1*ci1;
        }
    }
    float* P = Epart + (size_t)ks*2*NN*NN;
#pragma unroll
    for (int p = 0; p < 2; ++p) {
        const int i = i0 + ty*2 + p;
#pragma unroll
        for (int q = 0; q < 2; ++q) {
            const int j = j0 + tx*2 + q;
            P[(size_t)0*NN*NN + (size_t)i*NN + j] = accr[p][q];
            P[(size_t)1*NN*NN + (size_t)i*NN + j] = acci[p][q];
        }
    }
}

// ---------------------------------------------------------------------------
// Kernel 3: M = (sum_ks Epart[ks]) / c     with c = 1/(2 rhoX) + mu
// ---------------------------------------------------------------------------
__global__ __launch_bounds__(256) void reduceM_kernel(
    const float* __restrict__ Epart,
    const float* __restrict__ rhoX, const float* __restrict__ mu,
    float* __restrict__ Mm)
{
    const size_t idx = (size_t)blockIdx.x*256 + threadIdx.x;   // over 2*NN*NN
    const float cdiag = 1.f/(2.f*rhoX[0]) + mu[0];
    const float ic = 1.f/cdiag;
    const size_t pl = (size_t)2*NN*NN;
    float s = Epart[idx] + Epart[pl + idx] + Epart[2*pl + idx] + Epart[3*pl + idx];
    Mm[idx] = s * ic;
}

// ---------------------------------------------------------------------------
// Kernel 4: S0 = I - M   (elementwise, both planes)
// ---------------------------------------------------------------------------
__global__ __launch_bounds__(256) void initS_kernel(
    const float* __restrict__ Mm, float* __restrict__ S)
{
    const size_t idx = (size_t)blockIdx.x*256 + threadIdx.x;   // over NN*NN
    const int i = (int)(idx / NN), j = (int)(idx % NN);
    S[idx] = ((i == j) ? 1.f : 0.f) - Mm[idx];
    S[(size_t)NN*NN + idx] = -Mm[(size_t)NN*NN + idx];
}

// ---------------------------------------------------------------------------
// Kernel 5: Sout = I - M @ Sin   (complex 512x512x512, Horner step)
// grid (16,16), block 256, 32x32 tile, 2x2 per thread, l-chunks of 32
// ---------------------------------------------------------------------------
__global__ __launch_bounds__(256) void cgemm_kernel(
    const float* __restrict__ Mm, const float* __restrict__ Sin,
    float* __restrict__ Sout)
{
    const int i0 = blockIdx.y * 32;
    const int j0 = blockIdx.x * 32;
    const int tx = threadIdx.x & 15;
    const int ty = threadIdx.x >> 4;

    __shared__ float sMr[32][33], sMi[32][33];   // [i][l]
    __shared__ float sSr[32][33], sSi[32][33];   // [l][j]

    float accr[2][2] = {{0.f,0.f},{0.f,0.f}};
    float acci[2][2] = {{0.f,0.f},{0.f,0.f}};

    const int mr = threadIdx.x >> 3;        // 0..31
    const int mc = (threadIdx.x & 7) * 4;   // 0..28

    for (int l0 = 0; l0 < NN; l0 += 32) {
        f4 va = *(const f4*)(Mm  + (size_t)0*NN*NN + (size_t)(i0+mr)*NN + l0 + mc);
        f4 vb = *(const f4*)(Mm  + (size_t)1*NN*NN + (size_t)(i0+mr)*NN + l0 + mc);
        f4 vc = *(const f4*)(Sin + (size_t)0*NN*NN + (size_t)(l0+mr)*NN + j0 + mc);
        f4 vd = *(const f4*)(Sin + (size_t)1*NN*NN + (size_t)(l0+mr)*NN + j0 + mc);
        __syncthreads();
        sMr[mr][mc] = va.x; sMr[mr][mc+1] = va.y; sMr[mr][mc+2] = va.z; sMr[mr][mc+3] = va.w;
        sMi[mr][mc] = vb.x; sMi[mr][mc+1] = vb.y; sMi[mr][mc+2] = vb.z; sMi[mr][mc+3] = vb.w;
        sSr[mr][mc] = vc.x; sSr[mr][mc+1] = vc.y; sSr[mr][mc+2] = vc.z; sSr[mr][mc+3] = vc.w;
        sSi[mr][mc] = vd.x; sSi[mr][mc+1] = vd.y; sSi[mr][mc+2] = vd.z; sSi[mr][mc+3] = vd.w;
        __syncthreads();
#pragma unroll
        for (int l = 0; l < 32; ++l) {
            float ar0 = sMr[ty*2+0][l], ar1 = sMr[ty*2+1][l];
            float ai0 = sMi[ty*2+0][l], ai1 = sMi[ty*2+1][l];
            float br0 = sSr[l][tx*2+0], br1 = sSr[l][tx*2+1];
            float bi0 = sSi[l][tx*2+0], bi1 = sSi[l][tx*2+1];
            accr[0][0] += ar0*br0 - ai0*bi0;  acci[0][0] += ar0*bi0 + ai0*br0;
            accr[0][1] += ar0*br1 - ai0*bi1;  acci[0][1] += ar0*bi1 + ai0*br1;
            accr[1][0] += ar1*br0 - ai1*bi0;  acci[1][0] += ar1*bi0 + ai1*br0;
            accr[1][1] += ar1*br1 - ai1*bi1;  acci[1][1] += ar1*bi1 + ai1*br1;
        }
    }
#pragma unroll
    for (int p = 0; p < 2; ++p) {
        const int i = i0 + ty*2 + p;
#pragma unroll
        for (int q = 0; q < 2; ++q) {
            const int j = j0 + tx*2 + q;
            const float idv = (i == j) ? 1.f : 0.f;
            Sout[(size_t)0*NN*NN + (size_t)i*NN + j] = idv - accr[p][q];
            Sout[(size_t)1*NN*NN + (size_t)i*NN + j] = -acci[p][q];
        }
    }
}

// ---------------------------------------------------------------------------
// Kernel 6: X[k] = (S/c) @ Brho[k] + params4[k]
// grid (K, 8): per block one k and a 64-row group; 256 threads
// ---------------------------------------------------------------------------
__global__ __launch_bounds__(256) void final_kernel(
    const float* __restrict__ S, const float* __restrict__ Brho,
    const float* __restrict__ params4,
    const float* __restrict__ rhoX, const float* __restrict__ mu,
    float* __restrict__ Xout)
{
    const int k  = blockIdx.x;
    const int i0 = blockIdx.y * 64;
    const int r  = threadIdx.x & 63;
    const int dg = threadIdx.x >> 6;   // 0..3  (d = dg*4 .. dg*4+3)

    __shared__ float sSr[64][33], sSi[64][33];   // [i][l] chunk of 32
    __shared__ float sBr[32][17], sBi[32][17];   // [l][d]

    float accr[4] = {0.f,0.f,0.f,0.f};
    float acci[4] = {0.f,0.f,0.f,0.f};

    const int qr = threadIdx.x >> 2;        // 0..63
    const int qc = (threadIdx.x & 3) * 8;   // 0,8,16,24

    for (int l0 = 0; l0 < NN; l0 += 32) {
        f4 s0 = *(const f4*)(S + (size_t)0*NN*NN + (size_t)(i0+qr)*NN + l0 + qc);
        f4 s1 = *(const f4*)(S + (size_t)0*NN*NN + (size_t)(i0+qr)*NN + l0 + qc + 4);
        f4 s2 = *(const f4*)(S + (size_t)1*NN*NN + (size_t)(i0+qr)*NN + l0 + qc);
        f4 s3 = *(const f4*)(S + (size_t)1*NN*NN + (size_t)(i0+qr)*NN + l0 + qc + 4);
        f4 b0, b1;
        if (threadIdx.x < 128) {
            const int brw = threadIdx.x >> 2;        // 0..31
            const int bcl = (threadIdx.x & 3) * 4;   // 0,4,8,12
            b0 = *(const f4*)(Brho + ((size_t)k*2+0)*NN*DD + (size_t)(l0+brw)*DD + bcl);
            b1 = *(const f4*)(Brho + ((size_t)k*2+1)*NN*DD + (size_t)(l0+brw)*DD + bcl);
        }
        __syncthreads();
        sSr[qr][qc+0] = s0.x; sSr[qr][qc+1] = s0.y; sSr[qr][qc+2] = s0.z; sSr[qr][qc+3] = s0.w;
        sSr[qr][qc+4] = s1.x; sSr[qr][qc+5] = s1.y; sSr[qr][qc+6] = s1.z; sSr[qr][qc+7] = s1.w;
        sSi[qr][qc+0] = s2.x; sSi[qr][qc+1] = s2.y; sSi[qr][qc+2] = s2.z; sSi[qr][qc+3] = s2.w;
        sSi[qr][qc+4] = s3.x; sSi[qr][qc+5] = s3.y; sSi[qr][qc+6] = s3.z; sSi[qr][qc+7] = s3.w;
        if (threadIdx.x < 128) {
            const int brw = threadIdx.x >> 2;
            const int bcl = (threadIdx.x & 3) * 4;
            sBr[brw][bcl+0] = b0.x; sBr[brw][bcl+1] = b0.y; sBr[brw][bcl+2] = b0.z; sBr[brw][bcl+3] = b0.w;
            sBi[brw][bcl+0] = b1.x; sBi[brw][bcl+1] = b1.y; sBi[brw][bcl+2] = b1.z; sBi[brw][bcl+3] = b1.w;
        }
        __syncthreads();
#pragma unroll
        for (int l = 0; l < 32; ++l) {
            float ar = sSr[r][l], ai = sSi[r][l];
#pragma unroll
            for (int q = 0; q < 4; ++q) {
                float br = sBr[l][dg*4+q], bi = sBi[l][dg*4+q];
                accr[q] += ar*br - ai*bi;
                acci[q] += ar*bi + ai*br;
            }
        }
        __syncthreads();
    }
    const float cdiag = 1.f/(2.f*rhoX[0]) + mu[0];
    const float ic = 1.f/cdiag;
    const size_t base0 = ((size_t)k*2+0)*NN*DD + (size_t)(i0+r)*DD + dg*4;
    const size_t base1 = ((size_t)k*2+1)*NN*DD + (size_t)(i0+r)*DD + dg*4;
#pragma unroll
    for (int q = 0; q < 4; ++q) {
        Xout[base0+q] = accr[q]*ic + params4[base0+q];
        Xout[base1+q] = acci[q]*ic + params4[base1+q];
    }
}

// ---------------------------------------------------------------------------
extern "C" void kernel_launch(void* const* d_in, const int* in_sizes, int n_in,
                              void* d_out, int out_size, void* d_ws, size_t ws_size,
                              hipStream_t stream) {
    const float* H     = (const float*)d_in[0];
    const float* U_RF  = (const float*)d_in[1];
    const float* U_BB  = (const float*)d_in[2];
    const float* W     = (const float*)d_in[3];
    const float* V_RF  = (const float*)d_in[4];
    const float* V_BB  = (const float*)d_in[5];
    const float* Y     = (const float*)d_in[6];
    // d_in[7] = rho (unused by reference)
    const float* rhoX  = (const float*)d_in[8];
    const float* mu    = (const float*)d_in[9];
    const float* par4  = (const float*)d_in[10];
    float* Xout = (float*)d_out;

    float* ws = (float*)d_ws;
    const size_t planeKND = (size_t)KK*2*NN*DD;    // 8388608 floats
    const size_t planeNN  = (size_t)2*NN*NN;       // 524288 floats
    float* temp  = ws;
    float* TWb   = temp + planeKND;
    float* Brho  = TWb  + planeKND;
    float* Epart = Brho + planeKND;                // 4 * planeNN
    float* Mm    = Epart + 4*planeNN;
    float* S0    = Mm + planeNN;
    float* S1    = S0 + planeNN;

    prep_kernel<<<KK, 512, 0, stream>>>(H, U_RF, U_BB, W, V_RF, V_BB, Y, rhoX,
                                        temp, TWb, Brho);
    egemm_kernel<<<dim3(16,16,4), 256, 0, stream>>>(TWb, temp, Epart);
    reduceM_kernel<<<(int)(planeNN/256), 256, 0, stream>>>(Epart, rhoX, mu, Mm);
    initS_kernel<<<(int)((size_t)NN*NN/256), 256, 0, stream>>>(Mm, S0);

    float* sin_ = S0; float* sout_ = S1;
    for (int it = 0; it < 7; ++it) {               // Neumann degree 8
        cgemm_kernel<<<dim3(16,16), 256, 0, stream>>>(Mm, sin_, sout_);
        float* tp = sin_; sin_ = sout_; sout_ = tp;
    }
    final_kernel<<<dim3(KK, 8), 256, 0, stream>>>(sin_, Brho, par4, rhoX, mu, Xout);
}

// Round 2
// 380.888 us; speedup vs baseline: 3.2306x; 3.2306x over previous
//
#include <hip/hip_runtime.h>

#define KK 512
#define NN 512
#define DD 16
#define MM 64
#define MRF 16
#define NRF 64

typedef float4 f4;
typedef __attribute__((ext_vector_type(8))) short bf16x8;
typedef __attribute__((ext_vector_type(4))) float f32x4;
typedef __attribute__((ext_vector_type(8))) unsigned short u16x8;

#define MFMA16 __builtin_amdgcn_mfma_f32_16x16x32_bf16

static __device__ __forceinline__ unsigned short f2bf(float x) {
    unsigned int u = __float_as_uint(x);
    u += 0x7fffu + ((u >> 16) & 1u);
    return (unsigned short)(u >> 16);
}

static __device__ __forceinline__ void store_bf16_row16(unsigned short* dst, const float* v) {
    u16x8 a, b;
#pragma unroll
    for (int q = 0; q < 8; ++q) { a[q] = f2bf(v[q]); b[q] = f2bf(v[8 + q]); }
    *reinterpret_cast<u16x8*>(dst) = a;
    *reinterpret_cast<u16x8*>(dst + 8) = b;
}

// ---------------------------------------------------------------------------
// Kernel 1: per-k prep.  temp = conjT(H)@U_RF@U_BB ; TW = temp@W ;
//           Brho = TW + 0.5*(V_RF@V_BB/rhoX - Y)
// Outputs bf16: temp[k][2][n][16], TW[k][2][n][16], BrhoT[k][2][16][512]
// ---------------------------------------------------------------------------
__global__ __launch_bounds__(512) void prep_kernel(
    const float* __restrict__ H, const float* __restrict__ U_RF,
    const float* __restrict__ U_BB, const float* __restrict__ W,
    const float* __restrict__ V_RF, const float* __restrict__ V_BB,
    const float* __restrict__ Y, const float* __restrict__ rhoX,
    unsigned short* __restrict__ tempb, unsigned short* __restrict__ TWb,
    unsigned short* __restrict__ BTb)
{
    const int k = blockIdx.x;
    const int n = threadIdx.x;

    __shared__ float sUr[MM][MRF], sUi[MM][MRF];
    __shared__ float sUBr[MRF][DD], sUBi[MRF][DD];
    __shared__ float sWr[DD][DD], sWi[DD][DD];
    __shared__ float sVBr[NRF][DD], sVBi[NRF][DD];

    {
        const float* p = U_RF + (size_t)k*2*MM*MRF;
        for (int t = n; t < MM*MRF; t += 512) { sUr[t>>4][t&15] = p[t]; sUi[t>>4][t&15] = p[MM*MRF + t]; }
        const float* q = U_BB + (size_t)k*2*MRF*DD;
        for (int t = n; t < MRF*DD; t += 512) { sUBr[t>>4][t&15] = q[t]; sUBi[t>>4][t&15] = q[MRF*DD + t]; }
        const float* w = W + (size_t)k*2*DD*DD;
        for (int t = n; t < DD*DD; t += 512) { sWr[t>>4][t&15] = w[t]; sWi[t>>4][t&15] = w[DD*DD + t]; }
        const float* v = V_BB + (size_t)k*2*NRF*DD;
        for (int t = n; t < NRF*DD; t += 512) { sVBr[t>>4][t&15] = v[t]; sVBi[t>>4][t&15] = v[NRF*DD + t]; }
    }
    __syncthreads();

    // t[r] = sum_m conj(H[m,n]) * U_RF[m,r]
    float tr[MRF], ti[MRF];
#pragma unroll
    for (int r = 0; r < MRF; ++r) { tr[r] = 0.f; ti[r] = 0.f; }
    const float* Hr = H + ((size_t)k*2+0)*MM*NN + n;
    const float* Hi = H + ((size_t)k*2+1)*MM*NN + n;
#pragma unroll 4
    for (int m = 0; m < MM; ++m) {
        float hr = Hr[(size_t)m*NN];
        float hi = Hi[(size_t)m*NN];
#pragma unroll
        for (int r = 0; r < MRF; ++r) {
            float ur = sUr[m][r], ui = sUi[m][r];
            tr[r] += hr*ur + hi*ui;
            ti[r] += hr*ui - hi*ur;
        }
    }
    // temp[d] = sum_r t[r] * U_BB[r,d]
    float tmr[DD], tmi[DD];
#pragma unroll
    for (int d = 0; d < DD; ++d) { tmr[d] = 0.f; tmi[d] = 0.f; }
#pragma unroll
    for (int r = 0; r < MRF; ++r) {
        float ar = tr[r], ai = ti[r];
#pragma unroll
        for (int d = 0; d < DD; ++d) {
            float br = sUBr[r][d], bi = sUBi[r][d];
            tmr[d] += ar*br - ai*bi;
            tmi[d] += ar*bi + ai*br;
        }
    }
    store_bf16_row16(tempb + ((size_t)(k*2+0)*NN + n)*DD, tmr);
    store_bf16_row16(tempb + ((size_t)(k*2+1)*NN + n)*DD, tmi);

    // TW[d] = sum_dp temp[dp] * W[dp,d]
    float twr[DD], twi[DD];
#pragma unroll
    for (int d = 0; d < DD; ++d) { twr[d] = 0.f; twi[d] = 0.f; }
#pragma unroll
    for (int dp = 0; dp < DD; ++dp) {
        float ar = tmr[dp], ai = tmi[dp];
#pragma unroll
        for (int d = 0; d < DD; ++d) {
            float br = sWr[dp][d], bi = sWi[dp][d];
            twr[d] += ar*br - ai*bi;
            twi[d] += ar*bi + ai*br;
        }
    }
    store_bf16_row16(TWb + ((size_t)(k*2+0)*NN + n)*DD, twr);
    store_bf16_row16(TWb + ((size_t)(k*2+1)*NN + n)*DD, twi);

    // VV[d] = sum_r V_RF[n,r] * V_BB[r,d]
    float vvr[DD], vvi[DD];
#pragma unroll
    for (int d = 0; d < DD; ++d) { vvr[d] = 0.f; vvi[d] = 0.f; }
    const float* Vr = V_RF + (size_t)0*NN*NRF + (size_t)n*NRF;
    const float* Vi = V_RF + (size_t)1*NN*NRF + (size_t)n*NRF;
#pragma unroll 4
    for (int r = 0; r < NRF; ++r) {
        float vr = Vr[r], vi = Vi[r];
#pragma unroll
        for (int d = 0; d < DD; ++d) {
            vvr[d] += vr*sVBr[r][d] - vi*sVBi[r][d];
            vvi[d] += vr*sVBi[r][d] + vi*sVBr[r][d];
        }
    }
    const float irx = 1.f / rhoX[0];
    const float* Yr = Y + ((size_t)(k*2+0)*NN + n)*DD;
    const float* Yi = Y + ((size_t)(k*2+1)*NN + n)*DD;
    // BrhoT[k][p][d][n]
#pragma unroll
    for (int d = 0; d < DD; ++d) {
        float obr = twr[d] + 0.5f*(vvr[d]*irx - Yr[d]);
        float obi = twi[d] + 0.5f*(vvi[d]*irx - Yi[d]);
        BTb[((size_t)(k*2+0)*DD + d)*NN + n] = f2bf(obr);
        BTb[((size_t)(k*2+1)*DD + d)*NN + n] = f2bf(obi);
    }
}

// ---------------------------------------------------------------------------
// Kernel 2: Epart[ks] = sum_{kappa slice} TW @ temp^H  (complex 512x512, MFMA)
// grid (64, 8): x = ib*8+ks (same-A-panel blocks share XCD), y = jb
// block 256 = 4 waves (2x2), each wave 32x32 via 2x2 16x16 subtiles
// ---------------------------------------------------------------------------
__global__ __launch_bounds__(256) void egemm_kernel(
    const unsigned short* __restrict__ TWb, const unsigned short* __restrict__ tmpb,
    float* __restrict__ Epart)
{
    const int ib = blockIdx.x >> 3;
    const int ks = blockIdx.x & 7;
    const int jb = blockIdx.y;
    const int w    = threadIdx.x >> 6;
    const int lane = threadIdx.x & 63;
    const int m  = lane & 15;
    const int kg = lane >> 4;
    const int iw = ib*64 + (w>>1)*32;
    const int jw = jb*64 + (w&1)*32;
    const int d0  = (kg & 1) * 8;
    const int kof = kg >> 1;

    f32x4 RR[2][2], II[2][2], RI[2][2], IR[2][2];
#pragma unroll
    for (int is = 0; is < 2; ++is)
#pragma unroll
        for (int js = 0; js < 2; ++js) {
            RR[is][js] = (f32x4)0.f; II[is][js] = (f32x4)0.f;
            RI[is][js] = (f32x4)0.f; IR[is][js] = (f32x4)0.f;
        }

#pragma unroll 2
    for (int c = 0; c < 32; ++c) {
        const int chunk = ks*32 + c;
        const int kp = chunk*2 + kof;
        const unsigned short* Ab = TWb  + ((size_t)(kp*2+0)*NN + iw + m)*DD + d0;
        const unsigned short* Bb = tmpb + ((size_t)(kp*2+0)*NN + jw + m)*DD + d0;
        bf16x8 ar[2], ai[2], br[2], bi[2];
#pragma unroll
        for (int is = 0; is < 2; ++is) {
            ar[is] = *reinterpret_cast<const bf16x8*>(Ab + (size_t)is*16*DD);
            ai[is] = *reinterpret_cast<const bf16x8*>(Ab + (size_t)NN*DD + (size_t)is*16*DD);
        }
#pragma unroll
        for (int js = 0; js < 2; ++js) {
            br[js] = *reinterpret_cast<const bf16x8*>(Bb + (size_t)js*16*DD);
            bi[js] = *reinterpret_cast<const bf16x8*>(Bb + (size_t)NN*DD + (size_t)js*16*DD);
        }
#pragma unroll
        for (int is = 0; is < 2; ++is)
#pragma unroll
            for (int js = 0; js < 2; ++js) {
                RR[is][js] = MFMA16(ar[is], br[js], RR[is][js], 0, 0, 0);
                II[is][js] = MFMA16(ai[is], bi[js], II[is][js], 0, 0, 0);
                RI[is][js] = MFMA16(ar[is], bi[js], RI[is][js], 0, 0, 0);
                IR[is][js] = MFMA16(ai[is], br[js], IR[is][js], 0, 0, 0);
            }
    }

    float* Eb = Epart + (size_t)ks*2*NN*NN;
#pragma unroll
    for (int is = 0; is < 2; ++is)
#pragma unroll
        for (int js = 0; js < 2; ++js) {
            const int i = iw + is*16 + kg*4;
            const int j = jw + js*16 + m;
#pragma unroll
            for (int r = 0; r < 4; ++r) {
                Eb[(size_t)(i+r)*NN + j]               = RR[is][js][r] + II[is][js][r];
                Eb[(size_t)NN*NN + (size_t)(i+r)*NN + j] = IR[is][js][r] - RI[is][js][r];
            }
        }
}

// ---------------------------------------------------------------------------
// Kernel 3: M = (sum_ks Epart[ks])/c ; S0 = I - M ; S0T = (I - M)^T  (bf16)
// ---------------------------------------------------------------------------
__global__ __launch_bounds__(256) void reduceinit_kernel(
    const float* __restrict__ Epart,
    const float* __restrict__ rhoX, const float* __restrict__ mu,
    unsigned short* __restrict__ Mb, unsigned short* __restrict__ S0,
    unsigned short* __restrict__ S0T)
{
    const size_t idx = (size_t)blockIdx.x*256 + threadIdx.x;   // over 2*NN*NN
    const float ic = 1.f / (1.f/(2.f*rhoX[0]) + mu[0]);
    const size_t pl = (size_t)2*NN*NN;
    float s = 0.f;
#pragma unroll
    for (int ks = 0; ks < 8; ++ks) s += Epart[(size_t)ks*pl + idx];
    const float mm = s * ic;
    Mb[idx] = f2bf(mm);
    const int p = (int)(idx / ((size_t)NN*NN));
    const size_t rem = idx - (size_t)p*NN*NN;
    const int i = (int)(rem / NN), j = (int)(rem % NN);
    const float s0 = ((p == 0 && i == j) ? 1.f : 0.f) - mm;
    const unsigned short b = f2bf(s0);
    S0[idx] = b;
    S0T[(size_t)p*NN*NN + (size_t)j*NN + i] = b;
}

// ---------------------------------------------------------------------------
// Kernel 4: Sout = I - M @ Sin  (complex, MFMA; also writes Sout^T)
// grid (16,16), block 256 = 4 waves (2x2), each wave one 16x16 subtile
// ---------------------------------------------------------------------------
__global__ __launch_bounds__(256) void cgemm_kernel(
    const unsigned short* __restrict__ Mb, const unsigned short* __restrict__ SinT,
    unsigned short* __restrict__ Sout, unsigned short* __restrict__ SoutT)
{
    const int w    = threadIdx.x >> 6;
    const int lane = threadIdx.x & 63;
    const int m  = lane & 15;
    const int kg = lane >> 4;
    const int i0 = blockIdx.y*32 + (w>>1)*16;
    const int j0 = blockIdx.x*32 + (w&1)*16;

    f32x4 RR = (f32x4)0.f, II = (f32x4)0.f, RI = (f32x4)0.f, IR = (f32x4)0.f;

#pragma unroll 4
    for (int c = 0; c < 16; ++c) {
        const int l0 = c*32 + kg*8;
        const bf16x8 ar = *reinterpret_cast<const bf16x8*>(Mb   + (size_t)(i0+m)*NN + l0);
        const bf16x8 ai = *reinterpret_cast<const bf16x8*>(Mb   + (size_t)NN*NN + (size_t)(i0+m)*NN + l0);
        const bf16x8 br = *reinterpret_cast<const bf16x8*>(SinT + (size_t)(j0+m)*NN + l0);
        const bf16x8 bi = *reinterpret_cast<const bf16x8*>(SinT + (size_t)NN*NN + (size_t)(j0+m)*NN + l0);
        RR = MFMA16(ar, br, RR, 0, 0, 0);
        II = MFMA16(ai, bi, II, 0, 0, 0);
        RI = MFMA16(ar, bi, RI, 0, 0, 0);
        IR = MFMA16(ai, br, IR, 0, 0, 0);
    }
#pragma unroll
    for (int r = 0; r < 4; ++r) {
        const int i = i0 + kg*4 + r;
        const int j = j0 + m;
        const float sr = ((i == j) ? 1.f : 0.f) - RR[r] + II[r];
        const float si = -(RI[r] + IR[r]);
        const unsigned short hr = f2bf(sr), hi = f2bf(si);
        Sout[(size_t)i*NN + j] = hr;
        Sout[(size_t)NN*NN + (size_t)i*NN + j] = hi;
        SoutT[(size_t)j*NN + i] = hr;
        SoutT[(size_t)NN*NN + (size_t)j*NN + i] = hi;
    }
}

// ---------------------------------------------------------------------------
// Kernel 5: X[k] = (S @ Brho[k]) * ic + params4[k]   (MFMA)
// grid (K, 8): block = 4 waves, wave w -> rows i0 = by*64 + w*16, one k
// ---------------------------------------------------------------------------
__global__ __launch_bounds__(256) void final_kernel(
    const unsigned short* __restrict__ Sb, const unsigned short* __restrict__ BTb,
    const float* __restrict__ par4,
    const float* __restrict__ rhoX, const float* __restrict__ mu,
    float* __restrict__ Xout)
{
    const int k  = blockIdx.x;
    const int w    = threadIdx.x >> 6;
    const int lane = threadIdx.x & 63;
    const int m  = lane & 15;
    const int kg = lane >> 4;
    const int i0 = blockIdx.y*64 + w*16;

    f32x4 RR = (f32x4)0.f, II = (f32x4)0.f, RI = (f32x4)0.f, IR = (f32x4)0.f;

#pragma unroll 4
    for (int c = 0; c < 16; ++c) {
        const int l0 = c*32 + kg*8;
        const bf16x8 ar = *reinterpret_cast<const bf16x8*>(Sb  + (size_t)(i0+m)*NN + l0);
        const bf16x8 ai = *reinterpret_cast<const bf16x8*>(Sb  + (size_t)NN*NN + (size_t)(i0+m)*NN + l0);
        const bf16x8 br = *reinterpret_cast<const bf16x8*>(BTb + ((size_t)(k*2+0)*DD + m)*NN + l0);
        const bf16x8 bi = *reinterpret_cast<const bf16x8*>(BTb + ((size_t)(k*2+1)*DD + m)*NN + l0);
        RR = MFMA16(ar, br, RR, 0, 0, 0);
        II = MFMA16(ai, bi, II, 0, 0, 0);
        RI = MFMA16(ar, bi, RI, 0, 0, 0);
        IR = MFMA16(ai, br, IR, 0, 0, 0);
    }
    const float ic = 1.f / (1.f/(2.f*rhoX[0]) + mu[0]);
#pragma unroll
    for (int r = 0; r < 4; ++r) {
        const int i = i0 + kg*4 + r;
        const int d = m;
        const size_t idx0 = ((size_t)(k*2+0)*NN + i)*DD + d;
        const size_t idx1 = ((size_t)(k*2+1)*NN + i)*DD + d;
        Xout[idx0] = (RR[r] - II[r])*ic + par4[idx0];
        Xout[idx1] = (RI[r] + IR[r])*ic + par4[idx1];
    }
}

// ---------------------------------------------------------------------------
extern "C" void kernel_launch(void* const* d_in, const int* in_sizes, int n_in,
                              void* d_out, int out_size, void* d_ws, size_t ws_size,
                              hipStream_t stream) {
    const float* H     = (const float*)d_in[0];
    const float* U_RF  = (const float*)d_in[1];
    const float* U_BB  = (const float*)d_in[2];
    const float* W     = (const float*)d_in[3];
    const float* V_RF  = (const float*)d_in[4];
    const float* V_BB  = (const float*)d_in[5];
    const float* Y     = (const float*)d_in[6];
    // d_in[7] = rho (unused by reference)
    const float* rhoX  = (const float*)d_in[8];
    const float* mu    = (const float*)d_in[9];
    const float* par4  = (const float*)d_in[10];
    float* Xout = (float*)d_out;

    unsigned short* u = (unsigned short*)d_ws;
    const size_t bigE = (size_t)KK*2*NN*DD;    // 8,388,608 elems
    const size_t plE  = (size_t)2*NN*NN;       //   524,288 elems
    unsigned short* tempb = u;
    unsigned short* TWb   = tempb + bigE;
    unsigned short* BTb   = TWb + bigE;
    unsigned short* Mb    = BTb + bigE;
    unsigned short* S0    = Mb + plE;
    unsigned short* S0T   = S0 + plE;
    unsigned short* S1    = S0T + plE;
    unsigned short* S1T   = S1 + plE;
    float* Epart = (float*)(S1T + plE);        // 8 * plE floats (16.8 MB)

    prep_kernel<<<KK, 512, 0, stream>>>(H, U_RF, U_BB, W, V_RF, V_BB, Y, rhoX,
                                        tempb, TWb, BTb);
    egemm_kernel<<<dim3(64, 8), 256, 0, stream>>>(TWb, tempb, Epart);
    reduceinit_kernel<<<(int)(plE/256), 256, 0, stream>>>(Epart, rhoX, mu, Mb, S0, S0T);

    unsigned short* sin_  = S0; unsigned short* sinT_  = S0T;
    unsigned short* sout_ = S1; unsigned short* soutT_ = S1T;
    for (int it = 0; it < 8; ++it) {           // Neumann degree 9
        cgemm_kernel<<<dim3(16, 16), 256, 0, stream>>>(Mb, sinT_, sout_, soutT_);
        unsigned short* t1 = sin_;  sin_  = sout_;  sout_  = t1;
        unsigned short* t2 = sinT_; sinT_ = soutT_; soutT_ = t2;
    }
    final_kernel<<<dim3(KK, 8), 256, 0, stream>>>(sin_, BTb, par4, rhoX, mu, Xout);
}

// Round 3
// 267.641 us; speedup vs baseline: 4.5976x; 1.4231x over previous
//
#include <hip/hip_runtime.h>

#define KK 512
#define NN 512
#define DD 16
#define MM 64
#define MRF 16
#define NRF 64

typedef __attribute__((ext_vector_type(8))) short bf16x8;
typedef __attribute__((ext_vector_type(4))) float f32x4;
typedef __attribute__((ext_vector_type(8))) unsigned short u16x8;

#define MFMA16 __builtin_amdgcn_mfma_f32_16x16x32_bf16

static __device__ __forceinline__ unsigned short f2bf(float x) {
    unsigned int u = __float_as_uint(x);
    u += 0x7fffu + ((u >> 16) & 1u);
    return (unsigned short)(u >> 16);
}

// ---------------------------------------------------------------------------
// Kernel A: V_RF fp32 -> stacked bf16 rows VRFb[n][vr(64)|vi(64)]
// ---------------------------------------------------------------------------
__global__ __launch_bounds__(256) void vrfb_kernel(
    const float* __restrict__ V_RF, unsigned short* __restrict__ VRFb)
{
    const int idx = blockIdx.x*256 + threadIdx.x;   // 65536
    const int n = idx >> 7, j = idx & 127;
    const int p = j >> 6, r = j & 63;
    VRFb[idx] = f2bf(V_RF[((size_t)p*NN + n)*NRF + r]);
}

// ---------------------------------------------------------------------------
// Kernel B: per-k G = U_RF@U_BB, GW = G@W; emit stacked-sign bf16 B-rows:
//   GT2[k][set][d][128]: set0 [Gr|Gi] (temp_r), set1 [Gi|-Gr] (temp_i),
//                        set2 [GWr|GWi] (tw_r), set3 [GWi|-GWr] (tw_i)
//   VBT2[k][set][d][128]: set0 [VBr|-VBi] (vv_r), set1 [VBi|VBr] (vv_i)
// ---------------------------------------------------------------------------
__global__ __launch_bounds__(64) void small_kernel(
    const float* __restrict__ U_RF, const float* __restrict__ U_BB,
    const float* __restrict__ W, const float* __restrict__ V_BB,
    unsigned short* __restrict__ GT2, unsigned short* __restrict__ VBT2)
{
    const int k = blockIdx.x, t = threadIdx.x;
    __shared__ float sUB[2][MRF][DD], sW[2][DD][DD];
    __shared__ float sVB[2][NRF][DD];
    __shared__ float sG[2][MM][17], sGW[2][MM][17];

    const float* ub = U_BB + (size_t)k*2*MRF*DD;
    const float* ww = W    + (size_t)k*2*DD*DD;
    const float* vb = V_BB + (size_t)k*2*NRF*DD;
    for (int i = t; i < 2*MRF*DD; i += 64) sUB[i>>8][(i>>4)&15][i&15] = ub[i];
    for (int i = t; i < 2*DD*DD;  i += 64) sW[i>>8][(i>>4)&15][i&15]  = ww[i];
    for (int i = t; i < 2*NRF*DD; i += 64) sVB[i>>10][(i>>4)&63][i&15] = vb[i];
    __syncthreads();

    {   // thread = m
        const int m = t;
        const float* uf = U_RF + ((size_t)k*2*MM + m)*MRF;
        float ur[MRF], ui[MRF];
#pragma unroll
        for (int r = 0; r < MRF; ++r) { ur[r] = uf[r]; ui[r] = uf[(size_t)MM*MRF + r]; }
        float gr[DD], gi[DD];
#pragma unroll
        for (int d = 0; d < DD; ++d) { gr[d] = 0.f; gi[d] = 0.f; }
#pragma unroll
        for (int r = 0; r < MRF; ++r)
#pragma unroll
            for (int d = 0; d < DD; ++d) {
                gr[d] += ur[r]*sUB[0][r][d] - ui[r]*sUB[1][r][d];
                gi[d] += ur[r]*sUB[1][r][d] + ui[r]*sUB[0][r][d];
            }
        float gwr[DD], gwi[DD];
#pragma unroll
        for (int d = 0; d < DD; ++d) { gwr[d] = 0.f; gwi[d] = 0.f; }
#pragma unroll
        for (int dp = 0; dp < DD; ++dp)
#pragma unroll
            for (int d = 0; d < DD; ++d) {
                gwr[d] += gr[dp]*sW[0][dp][d] - gi[dp]*sW[1][dp][d];
                gwi[d] += gr[dp]*sW[1][dp][d] + gi[dp]*sW[0][dp][d];
            }
#pragma unroll
        for (int d = 0; d < DD; ++d) {
            sG[0][m][d] = gr[d];  sG[1][m][d] = gi[d];
            sGW[0][m][d] = gwr[d]; sGW[1][m][d] = gwi[d];
        }
    }
    __syncthreads();

    {   // GT2 rows: thread t -> set s, col d
        const int s = t >> 4, d = t & 15;
        unsigned short* dst = GT2 + (((size_t)k*4 + s)*DD + d)*128;
        const float (*P)[MM][17] = (s < 2) ? sG : sGW;
        const int im = s & 1;
        for (int cb = 0; cb < 16; ++cb) {
            u16x8 pk;
#pragma unroll
            for (int q = 0; q < 8; ++q) {
                const int c = cb*8 + q;
                const int m = c & 63, hi = c >> 6;
                float v;
                if (!im) v = hi ? P[1][m][d] : P[0][m][d];
                else     v = hi ? -P[0][m][d] : P[1][m][d];
                pk[q] = f2bf(v);
            }
            *reinterpret_cast<u16x8*>(dst + cb*8) = pk;
        }
    }
    if (t < 32) {   // VBT2 rows
        const int s = t >> 4, d = t & 15;
        unsigned short* dst = VBT2 + (((size_t)k*2 + s)*DD + d)*128;
        for (int cb = 0; cb < 16; ++cb) {
            u16x8 pk;
#pragma unroll
            for (int q = 0; q < 8; ++q) {
                const int c = cb*8 + q;
                const int r = c & 63, hi = c >> 6;
                float v;
                if (s == 0) v = hi ? -sVB[1][r][d] : sVB[0][r][d];
                else        v = hi ?  sVB[0][r][d] : sVB[1][r][d];
                pk[q] = f2bf(v);
            }
            *reinterpret_cast<u16x8*>(dst + cb*8) = pk;
        }
    }
}

// ---------------------------------------------------------------------------
// Kernel C: prep_main. grid (K, 2 n-halves), 256 thr = 4 waves.
// Stage H[k][*][*][n-half] into LDS as bf16 stacked rows [hr|hi] (XOR swizzle),
// MFMA: temp/TW = conj(H)*G / *GW ; VV = V_RF@V_BB ; emit temp,TW,B (bf16).
// ---------------------------------------------------------------------------
__global__ __launch_bounds__(256, 1) void prep_main(
    const float* __restrict__ H, const unsigned short* __restrict__ GT2,
    const unsigned short* __restrict__ VBT2, const unsigned short* __restrict__ VRFb,
    const float* __restrict__ Y, const float* __restrict__ rhoX,
    unsigned short* __restrict__ tempb, unsigned short* __restrict__ TWb,
    unsigned short* __restrict__ Bb)
{
    const int k  = blockIdx.x;
    const int nh = blockIdx.y;              // n-half: 0 or 1
    __shared__ __align__(16) unsigned short sHT[256*128];   // 64 KB, rows 256B

    // ---- stage: H[k][p][m][nh*256 + n'] -> sHT[n'][p*64+m] bf16, swizzled
    const float* Hk = H + (size_t)k*2*MM*NN + nh*256;
#pragma unroll 16
    for (int q = 0; q < 128; ++q) {
        const int idx = q*256 + threadIdx.x;      // 0..32767
        const int np = idx & 255;                 // n'
        const int mp = idx >> 8;                  // p*64+m, 0..127
        const float v = Hk[(size_t)mp*NN + np];
        const int byte = np*256 + ((mp*2) ^ ((np & 7) << 4));
        *reinterpret_cast<unsigned short*>(reinterpret_cast<char*>(sHT) + byte) = f2bf(v);
    }
    __syncthreads();

    const int w = threadIdx.x >> 6, lane = threadIdx.x & 63;
    const int j = lane & 15, kg = lane >> 4;
    const float irx = 1.f / rhoX[0];

    // resident B-fragments (global, tiny, L2-hot)
    bf16x8 BG[4][4], BV[2][4];
#pragma unroll
    for (int s = 0; s < 4; ++s)
#pragma unroll
        for (int ks = 0; ks < 4; ++ks)
            BG[s][ks] = *reinterpret_cast<const bf16x8*>(
                GT2 + (((size_t)k*4 + s)*DD + j)*128 + ks*32 + kg*8);
#pragma unroll
    for (int s = 0; s < 2; ++s)
#pragma unroll
        for (int ks = 0; ks < 4; ++ks)
            BV[s][ks] = *reinterpret_cast<const bf16x8*>(
                VBT2 + (((size_t)k*2 + s)*DD + j)*128 + ks*32 + kg*8);

    for (int s8 = 0; s8 < 4; ++s8) {
        const int n0 = w*64 + s8*16;              // within half
        const int row = n0 + j;                   // n0&7==0 so row&7 == j&7
        bf16x8 AH[4], AV[4];
#pragma unroll
        for (int ks = 0; ks < 4; ++ks) {
            const int byte = row*256 + (((ks*32 + kg*8)*2) ^ ((row & 7) << 4));
            AH[ks] = *reinterpret_cast<const bf16x8*>(
                reinterpret_cast<const char*>(sHT) + byte);
            AV[ks] = *reinterpret_cast<const bf16x8*>(
                VRFb + (size_t)(nh*256 + row)*128 + ks*32 + kg*8);
        }
        f32x4 aTr = (f32x4)0.f, aTi = (f32x4)0.f;
        f32x4 aWr = (f32x4)0.f, aWi = (f32x4)0.f;
        f32x4 aVr = (f32x4)0.f, aVi = (f32x4)0.f;
#pragma unroll
        for (int ks = 0; ks < 4; ++ks) {
            aTr = MFMA16(AH[ks], BG[0][ks], aTr, 0, 0, 0);
            aTi = MFMA16(AH[ks], BG[1][ks], aTi, 0, 0, 0);
            aWr = MFMA16(AH[ks], BG[2][ks], aWr, 0, 0, 0);
            aWi = MFMA16(AH[ks], BG[3][ks], aWi, 0, 0, 0);
            aVr = MFMA16(AV[ks], BV[0][ks], aVr, 0, 0, 0);
            aVi = MFMA16(AV[ks], BV[1][ks], aVi, 0, 0, 0);
        }
        // epilogue: C/D layout col = lane&15 = d, row = kg*4+r = n-offset
        const int d = j;
#pragma unroll
        for (int r = 0; r < 4; ++r) {
            const int n = nh*256 + n0 + kg*4 + r;
            const size_t i0 = ((size_t)(k*2 + 0)*NN + n)*DD + d;
            const size_t i1 = ((size_t)(k*2 + 1)*NN + n)*DD + d;
            tempb[i0] = f2bf(aTr[r]); tempb[i1] = f2bf(aTi[r]);
            TWb[i0]   = f2bf(aWr[r]); TWb[i1]   = f2bf(aWi[r]);
            const float br_ = aWr[r] + 0.5f*(aVr[r]*irx - Y[i0]);
            const float bi_ = aWi[r] + 0.5f*(aVi[r]*irx - Y[i1]);
            Bb[i0] = f2bf(br_); Bb[i1] = f2bf(bi_);
        }
    }
}

// ---------------------------------------------------------------------------
// Kernel D: Epart[ks] = sum_{kappa slice} TW @ temp^H  (complex 512x512, MFMA)
// ---------------------------------------------------------------------------
__global__ __launch_bounds__(256) void egemm_kernel(
    const unsigned short* __restrict__ TWb, const unsigned short* __restrict__ tmpb,
    float* __restrict__ Epart)
{
    const int ib = blockIdx.x >> 3;
    const int ks = blockIdx.x & 7;
    const int jb = blockIdx.y;
    const int w    = threadIdx.x >> 6;
    const int lane = threadIdx.x & 63;
    const int m  = lane & 15;
    const int kg = lane >> 4;
    const int iw = ib*64 + (w>>1)*32;
    const int jw = jb*64 + (w&1)*32;
    const int d0  = (kg & 1) * 8;
    const int kof = kg >> 1;

    f32x4 RR[2][2], II[2][2], RI[2][2], IR[2][2];
#pragma unroll
    for (int is = 0; is < 2; ++is)
#pragma unroll
        for (int js = 0; js < 2; ++js) {
            RR[is][js] = (f32x4)0.f; II[is][js] = (f32x4)0.f;
            RI[is][js] = (f32x4)0.f; IR[is][js] = (f32x4)0.f;
        }

#pragma unroll 2
    for (int c = 0; c < 32; ++c) {
        const int chunk = ks*32 + c;
        const int kp = chunk*2 + kof;
        const unsigned short* Ab = TWb  + ((size_t)(kp*2+0)*NN + iw + m)*DD + d0;
        const unsigned short* Bb2 = tmpb + ((size_t)(kp*2+0)*NN + jw + m)*DD + d0;
        bf16x8 ar[2], ai[2], br[2], bi[2];
#pragma unroll
        for (int is = 0; is < 2; ++is) {
            ar[is] = *reinterpret_cast<const bf16x8*>(Ab + (size_t)is*16*DD);
            ai[is] = *reinterpret_cast<const bf16x8*>(Ab + (size_t)NN*DD + (size_t)is*16*DD);
        }
#pragma unroll
        for (int js = 0; js < 2; ++js) {
            br[js] = *reinterpret_cast<const bf16x8*>(Bb2 + (size_t)js*16*DD);
            bi[js] = *reinterpret_cast<const bf16x8*>(Bb2 + (size_t)NN*DD + (size_t)js*16*DD);
        }
#pragma unroll
        for (int is = 0; is < 2; ++is)
#pragma unroll
            for (int js = 0; js < 2; ++js) {
                RR[is][js] = MFMA16(ar[is], br[js], RR[is][js], 0, 0, 0);
                II[is][js] = MFMA16(ai[is], bi[js], II[is][js], 0, 0, 0);
                RI[is][js] = MFMA16(ar[is], bi[js], RI[is][js], 0, 0, 0);
                IR[is][js] = MFMA16(ai[is], br[js], IR[is][js], 0, 0, 0);
            }
    }

    float* Eb = Epart + (size_t)ks*2*NN*NN;
#pragma unroll
    for (int is = 0; is < 2; ++is)
#pragma unroll
        for (int js = 0; js < 2; ++js) {
            const int i = iw + is*16 + kg*4;
            const int jx = jw + js*16 + m;
#pragma unroll
            for (int r = 0; r < 4; ++r) {
                Eb[(size_t)(i+r)*NN + jx]               = RR[is][js][r] + II[is][js][r];
                Eb[(size_t)NN*NN + (size_t)(i+r)*NN + jx] = IR[is][js][r] - RI[is][js][r];
            }
        }
}

// ---------------------------------------------------------------------------
// Kernel E: M = (sum Epart)/c ; S0 = I - M ; S0T  (bf16)
// ---------------------------------------------------------------------------
__global__ __launch_bounds__(256) void reduceinit_kernel(
    const float* __restrict__ Epart,
    const float* __restrict__ rhoX, const float* __restrict__ mu,
    unsigned short* __restrict__ Mb, unsigned short* __restrict__ S0,
    unsigned short* __restrict__ S0T)
{
    const size_t idx = (size_t)blockIdx.x*256 + threadIdx.x;   // over 2*NN*NN
    const float ic = 1.f / (1.f/(2.f*rhoX[0]) + mu[0]);
    const size_t pl = (size_t)2*NN*NN;
    float s = 0.f;
#pragma unroll
    for (int ks = 0; ks < 8; ++ks) s += Epart[(size_t)ks*pl + idx];
    const float mm = s * ic;
    Mb[idx] = f2bf(mm);
    const int p = (int)(idx / ((size_t)NN*NN));
    const size_t rem = idx - (size_t)p*NN*NN;
    const int i = (int)(rem / NN), jx = (int)(rem % NN);
    const float s0 = ((p == 0 && i == jx) ? 1.f : 0.f) - mm;
    const unsigned short b = f2bf(s0);
    S0[idx] = b;
    S0T[(size_t)p*NN*NN + (size_t)jx*NN + i] = b;
}

// ---------------------------------------------------------------------------
// Kernel F: Sout = I - M @ Sin  (complex MFMA; also writes Sout^T)
// ---------------------------------------------------------------------------
__global__ __launch_bounds__(256) void cgemm_kernel(
    const unsigned short* __restrict__ Mb, const unsigned short* __restrict__ SinT,
    unsigned short* __restrict__ Sout, unsigned short* __restrict__ SoutT)
{
    const int w    = threadIdx.x >> 6;
    const int lane = threadIdx.x & 63;
    const int m  = lane & 15;
    const int kg = lane >> 4;
    const int i0 = blockIdx.y*32 + (w>>1)*16;
    const int j0 = blockIdx.x*32 + (w&1)*16;

    f32x4 RR = (f32x4)0.f, II = (f32x4)0.f, RI = (f32x4)0.f, IR = (f32x4)0.f;

#pragma unroll 4
    for (int c = 0; c < 16; ++c) {
        const int l0 = c*32 + kg*8;
        const bf16x8 ar = *reinterpret_cast<const bf16x8*>(Mb   + (size_t)(i0+m)*NN + l0);
        const bf16x8 ai = *reinterpret_cast<const bf16x8*>(Mb   + (size_t)NN*NN + (size_t)(i0+m)*NN + l0);
        const bf16x8 br = *reinterpret_cast<const bf16x8*>(SinT + (size_t)(j0+m)*NN + l0);
        const bf16x8 bi = *reinterpret_cast<const bf16x8*>(SinT + (size_t)NN*NN + (size_t)(j0+m)*NN + l0);
        RR = MFMA16(ar, br, RR, 0, 0, 0);
        II = MFMA16(ai, bi, II, 0, 0, 0);
        RI = MFMA16(ar, bi, RI, 0, 0, 0);
        IR = MFMA16(ai, br, IR, 0, 0, 0);
    }
#pragma unroll
    for (int r = 0; r < 4; ++r) {
        const int i = i0 + kg*4 + r;
        const int jx = j0 + m;
        const float sr = ((i == jx) ? 1.f : 0.f) - RR[r] + II[r];
        const float si = -(RI[r] + IR[r]);
        const unsigned short hr = f2bf(sr), hi = f2bf(si);
        Sout[(size_t)i*NN + jx] = hr;
        Sout[(size_t)NN*NN + (size_t)i*NN + jx] = hi;
        SoutT[(size_t)jx*NN + i] = hr;
        SoutT[(size_t)NN*NN + (size_t)jx*NN + i] = hi;
    }
}

// ---------------------------------------------------------------------------
// Kernel G: X[k] = (S @ B[k]) * ic + params4[k]  (MFMA; B transposed in LDS)
// ---------------------------------------------------------------------------
__global__ __launch_bounds__(256) void final_kernel(
    const unsigned short* __restrict__ Sb, const unsigned short* __restrict__ Bb,
    const float* __restrict__ par4,
    const float* __restrict__ rhoX, const float* __restrict__ mu,
    float* __restrict__ Xout)
{
    const int k = blockIdx.x;
    __shared__ __align__(16) unsigned short sBT[2][DD][520];

    {   // stage + transpose B[k] ([2][512][16] -> [2][16][512])
        const unsigned short* Bk = Bb + (size_t)k*2*NN*DD;
        for (int q = 0; q < 8; ++q) {
            const int t8 = q*256 + threadIdx.x;    // 0..2047
            const u16x8 v = *reinterpret_cast<const u16x8*>(Bk + (size_t)t8*8);
            const int flat = t8*8;
            const int p = flat >> 13, n = (flat >> 4) & 511, dd0 = flat & 15;
#pragma unroll
            for (int jj = 0; jj < 8; ++jj) sBT[p][dd0+jj][n] = v[jj];
        }
    }
    __syncthreads();

    const int w    = threadIdx.x >> 6;
    const int lane = threadIdx.x & 63;
    const int m  = lane & 15;
    const int kg = lane >> 4;
    const int i0 = blockIdx.y*64 + w*16;

    f32x4 RR = (f32x4)0.f, II = (f32x4)0.f, RI = (f32x4)0.f, IR = (f32x4)0.f;

#pragma unroll 4
    for (int c = 0; c < 16; ++c) {
        const int l0 = c*32 + kg*8;
        const bf16x8 ar = *reinterpret_cast<const bf16x8*>(Sb + (size_t)(i0+m)*NN + l0);
        const bf16x8 ai = *reinterpret_cast<const bf16x8*>(Sb + (size_t)NN*NN + (size_t)(i0+m)*NN + l0);
        const bf16x8 br = *reinterpret_cast<const bf16x8*>(&sBT[0][m][l0]);
        const bf16x8 bi = *reinterpret_cast<const bf16x8*>(&sBT[1][m][l0]);
        RR = MFMA16(ar, br, RR, 0, 0, 0);
        II = MFMA16(ai, bi, II, 0, 0, 0);
        RI = MFMA16(ar, bi, RI, 0, 0, 0);
        IR = MFMA16(ai, br, IR, 0, 0, 0);
    }
    const float ic = 1.f / (1.f/(2.f*rhoX[0]) + mu[0]);
#pragma unroll
    for (int r = 0; r < 4; ++r) {
        const int i = i0 + kg*4 + r;
        const int d = m;
        const size_t idx0 = ((size_t)(k*2+0)*NN + i)*DD + d;
        const size_t idx1 = ((size_t)(k*2+1)*NN + i)*DD + d;
        Xout[idx0] = (RR[r] - II[r])*ic + par4[idx0];
        Xout[idx1] = (RI[r] + IR[r])*ic + par4[idx1];
    }
}

// ---------------------------------------------------------------------------
extern "C" void kernel_launch(void* const* d_in, const int* in_sizes, int n_in,
                              void* d_out, int out_size, void* d_ws, size_t ws_size,
                              hipStream_t stream) {
    const float* H     = (const float*)d_in[0];
    const float* U_RF  = (const float*)d_in[1];
    const float* U_BB  = (const float*)d_in[2];
    const float* W     = (const float*)d_in[3];
    const float* V_RF  = (const float*)d_in[4];
    const float* V_BB  = (const float*)d_in[5];
    const float* Y     = (const float*)d_in[6];
    // d_in[7] = rho (unused by reference)
    const float* rhoX  = (const float*)d_in[8];
    const float* mu    = (const float*)d_in[9];
    const float* par4  = (const float*)d_in[10];
    float* Xout = (float*)d_out;

    unsigned short* u = (unsigned short*)d_ws;
    const size_t bigE = (size_t)KK*2*NN*DD;    // 8,388,608
    const size_t plE  = (size_t)2*NN*NN;       //   524,288
    unsigned short* tempb = u;
    unsigned short* TWb   = tempb + bigE;
    unsigned short* Bb    = TWb + bigE;
    unsigned short* GT2   = Bb + bigE;                         // 512*4*16*128
    unsigned short* VBT2  = GT2 + (size_t)KK*4*DD*128;         // 512*2*16*128
    unsigned short* VRFb  = VBT2 + (size_t)KK*2*DD*128;        // 512*128
    unsigned short* Mb    = VRFb + (size_t)NN*128;
    unsigned short* S0    = Mb + plE;
    unsigned short* S0T   = S0 + plE;
    unsigned short* S1    = S0T + plE;
    unsigned short* S1T   = S1 + plE;
    float* Epart = (float*)(S1T + plE);                        // 8*plE floats

    vrfb_kernel<<<256, 256, 0, stream>>>(V_RF, VRFb);
    small_kernel<<<KK, 64, 0, stream>>>(U_RF, U_BB, W, V_BB, GT2, VBT2);
    prep_main<<<dim3(KK, 2), 256, 0, stream>>>(H, GT2, VBT2, VRFb, Y, rhoX,
                                               tempb, TWb, Bb);
    egemm_kernel<<<dim3(64, 8), 256, 0, stream>>>(TWb, tempb, Epart);
    reduceinit_kernel<<<(int)(plE/256), 256, 0, stream>>>(Epart, rhoX, mu, Mb, S0, S0T);

    unsigned short* sin_  = S0; unsigned short* sinT_  = S0T;
    unsigned short* sout_ = S1; unsigned short* soutT_ = S1T;
    for (int it = 0; it < 7; ++it) {           // Neumann degree 8
        cgemm_kernel<<<dim3(16, 16), 256, 0, stream>>>(Mb, sinT_, sout_, soutT_);
        unsigned short* t1 = sin_;  sin_  = sout_;  sout_  = t1;
        unsigned short* t2 = sinT_; sinT_ = soutT_; soutT_ = t2;
    }
    final_kernel<<<dim3(KK, 8), 256, 0, stream>>>(sin_, Bb, par4, rhoX, mu, Xout);
}

// Round 4
// 253.308 us; speedup vs baseline: 4.8578x; 1.0566x over previous
//
#include <hip/hip_runtime.h>

#define KK 512
#define NN 512
#define DD 16
#define MM 64
#define MRF 16
#define NRF 64

typedef __attribute__((ext_vector_type(8))) short bf16x8;
typedef __attribute__((ext_vector_type(4))) float f32x4;
typedef __attribute__((ext_vector_type(8))) unsigned short u16x8;

#define MFMA16 __builtin_amdgcn_mfma_f32_16x16x32_bf16

static __device__ __forceinline__ unsigned short f2bf(float x) {
    unsigned int u = __float_as_uint(x);
    u += 0x7fffu + ((u >> 16) & 1u);
    return (unsigned short)(u >> 16);
}

// ---------------------------------------------------------------------------
// Kernel A: V_RF fp32 -> stacked bf16 rows VRFb[n][vr(64)|vi(64)]
// ---------------------------------------------------------------------------
__global__ __launch_bounds__(256) void vrfb_kernel(
    const float* __restrict__ V_RF, unsigned short* __restrict__ VRFb)
{
    const int idx = blockIdx.x*256 + threadIdx.x;   // 65536
    const int n = idx >> 7, j = idx & 127;
    const int p = j >> 6, r = j & 63;
    VRFb[idx] = f2bf(V_RF[((size_t)p*NN + n)*NRF + r]);
}

// ---------------------------------------------------------------------------
// Kernel B: per-k G = U_RF@U_BB, GW = G@W; emit stacked-sign bf16 B-rows.
// 256 threads / 4 waves per block (was 64/1 — occupancy 5.5%, 102us).
//   GT2[k][set][d][128]: set0 [Gr|Gi], set1 [Gi|-Gr], set2 [GWr|GWi],
//                        set3 [GWi|-GWr]
//   VBT2[k][set][d][128]: set0 [VBr|-VBi], set1 [VBi|VBr]
// ---------------------------------------------------------------------------
__global__ __launch_bounds__(256) void small_kernel(
    const float* __restrict__ U_RF, const float* __restrict__ U_BB,
    const float* __restrict__ W, const float* __restrict__ V_BB,
    unsigned short* __restrict__ GT2, unsigned short* __restrict__ VBT2)
{
    const int k = blockIdx.x, t = threadIdx.x;
    __shared__ float sUR[2][MM][17];
    __shared__ float sUB[2][MRF][DD], sW[2][DD][DD];
    __shared__ float sVB[2][NRF][17];
    __shared__ float sG[2][MM][17], sGW[2][MM][17];

    const float* uf = U_RF + (size_t)k*2*MM*MRF;
    for (int i = t; i < 2*MM*MRF; i += 256) sUR[i>>10][(i>>4)&63][i&15] = uf[i];
    const float* ub = U_BB + (size_t)k*2*MRF*DD;
    for (int i = t; i < 2*MRF*DD; i += 256) sUB[i>>8][(i>>4)&15][i&15] = ub[i];
    const float* ww = W + (size_t)k*2*DD*DD;
    for (int i = t; i < 2*DD*DD; i += 256) sW[i>>8][(i>>4)&15][i&15] = ww[i];
    const float* vb = V_BB + (size_t)k*2*NRF*DD;
    for (int i = t; i < 2*NRF*DD; i += 256) sVB[i>>10][(i>>4)&63][i&15] = vb[i];
    __syncthreads();

    // Phase 1: G[m][d]  (thread = (m, d-quad))
    {
        const int m = t >> 2, dq = (t & 3) * 4;
        float gr[4] = {0,0,0,0}, gi[4] = {0,0,0,0};
#pragma unroll
        for (int r = 0; r < MRF; ++r) {
            const float ur = sUR[0][m][r], ui = sUR[1][m][r];
#pragma unroll
            for (int q = 0; q < 4; ++q) {
                const float br = sUB[0][r][dq+q], bi = sUB[1][r][dq+q];
                gr[q] += ur*br - ui*bi;
                gi[q] += ur*bi + ui*br;
            }
        }
#pragma unroll
        for (int q = 0; q < 4; ++q) { sG[0][m][dq+q] = gr[q]; sG[1][m][dq+q] = gi[q]; }
    }
    __syncthreads();

    // Phase 2: GW = G @ W
    {
        const int m = t >> 2, dq = (t & 3) * 4;
        float gwr[4] = {0,0,0,0}, gwi[4] = {0,0,0,0};
#pragma unroll
        for (int dp = 0; dp < DD; ++dp) {
            const float gr = sG[0][m][dp], gi = sG[1][m][dp];
#pragma unroll
            for (int q = 0; q < 4; ++q) {
                const float wr = sW[0][dp][dq+q], wi = sW[1][dp][dq+q];
                gwr[q] += gr*wr - gi*wi;
                gwi[q] += gr*wi + gi*wr;
            }
        }
#pragma unroll
        for (int q = 0; q < 4; ++q) { sGW[0][m][dq+q] = gwr[q]; sGW[1][m][dq+q] = gwi[q]; }
    }
    __syncthreads();

    // Phase 3: pack GT2. 64 rows (s,d) x 4 threads; c = cb*32 + cq*8 + q so
    // same-row lanes read m offset by 8 (bank-spread, not same-bank).
    {
        const int row = t >> 2, cq = t & 3;
        const int s = row >> 4, d = row & 15;
        const float (*P)[MM][17] = (s < 2) ? sG : sGW;
        const int im = s & 1;
        unsigned short* dst = GT2 + (((size_t)k*4 + s)*DD + d)*128;
#pragma unroll
        for (int cb = 0; cb < 4; ++cb) {
            u16x8 pk;
#pragma unroll
            for (int q = 0; q < 8; ++q) {
                const int c = cb*32 + cq*8 + q;
                const int m = c & 63, hi = c >> 6;
                float v;
                if (!im) v = hi ? P[1][m][d] : P[0][m][d];
                else     v = hi ? -P[0][m][d] : P[1][m][d];
                pk[q] = f2bf(v);
            }
            *reinterpret_cast<u16x8*>(dst + cb*32 + cq*8) = pk;
        }
    }
    // Phase 4: pack VBT2. 32 rows x 8 threads; c = cb*64 + cq*8 + q.
    {
        const int row = t >> 3, cq = t & 7;
        const int s = row >> 4, d = row & 15;
        unsigned short* dst = VBT2 + (((size_t)k*2 + s)*DD + d)*128;
#pragma unroll
        for (int cb = 0; cb < 2; ++cb) {
            u16x8 pk;
#pragma unroll
            for (int q = 0; q < 8; ++q) {
                const int c = cb*64 + cq*8 + q;
                const int r = c & 63, hi = c >> 6;
                float v;
                if (s == 0) v = hi ? -sVB[1][r][d] : sVB[0][r][d];
                else        v = hi ?  sVB[0][r][d] : sVB[1][r][d];
                pk[q] = f2bf(v);
            }
            *reinterpret_cast<u16x8*>(dst + cb*64 + cq*8) = pk;
        }
    }
}

// ---------------------------------------------------------------------------
// Kernel C: prep_main. grid (K, 2 n-halves), 256 thr = 4 waves.
// Stage H[k][*][*][n-half] into LDS as bf16 stacked rows [hr|hi] (XOR swizzle),
// MFMA: temp/TW = conj(H)*G / *GW ; VV = V_RF@V_BB ; emit temp,TW,B (bf16).
// ---------------------------------------------------------------------------
__global__ __launch_bounds__(256, 1) void prep_main(
    const float* __restrict__ H, const unsigned short* __restrict__ GT2,
    const unsigned short* __restrict__ VBT2, const unsigned short* __restrict__ VRFb,
    const float* __restrict__ Y, const float* __restrict__ rhoX,
    unsigned short* __restrict__ tempb, unsigned short* __restrict__ TWb,
    unsigned short* __restrict__ Bb)
{
    const int k  = blockIdx.x;
    const int nh = blockIdx.y;              // n-half: 0 or 1
    __shared__ __align__(16) unsigned short sHT[256*128];   // 64 KB, rows 256B

    // ---- stage: H[k][p][m][nh*256 + n'] -> sHT[n'][p*64+m] bf16, swizzled
    const float* Hk = H + (size_t)k*2*MM*NN + nh*256;
#pragma unroll 16
    for (int q = 0; q < 128; ++q) {
        const int idx = q*256 + threadIdx.x;      // 0..32767
        const int np = idx & 255;                 // n'
        const int mp = idx >> 8;                  // p*64+m, 0..127
        const float v = Hk[(size_t)mp*NN + np];
        const int byte = np*256 + ((mp*2) ^ ((np & 7) << 4));
        *reinterpret_cast<unsigned short*>(reinterpret_cast<char*>(sHT) + byte) = f2bf(v);
    }
    __syncthreads();

    const int w = threadIdx.x >> 6, lane = threadIdx.x & 63;
    const int j = lane & 15, kg = lane >> 4;
    const float irx = 1.f / rhoX[0];

    // resident B-fragments (global, tiny, L2-hot)
    bf16x8 BG[4][4], BV[2][4];
#pragma unroll
    for (int s = 0; s < 4; ++s)
#pragma unroll
        for (int ks = 0; ks < 4; ++ks)
            BG[s][ks] = *reinterpret_cast<const bf16x8*>(
                GT2 + (((size_t)k*4 + s)*DD + j)*128 + ks*32 + kg*8);
#pragma unroll
    for (int s = 0; s < 2; ++s)
#pragma unroll
        for (int ks = 0; ks < 4; ++ks)
            BV[s][ks] = *reinterpret_cast<const bf16x8*>(
                VBT2 + (((size_t)k*2 + s)*DD + j)*128 + ks*32 + kg*8);

    for (int s8 = 0; s8 < 4; ++s8) {
        const int n0 = w*64 + s8*16;              // within half
        const int row = n0 + j;                   // n0&7==0 so row&7 == j&7
        bf16x8 AH[4], AV[4];
#pragma unroll
        for (int ks = 0; ks < 4; ++ks) {
            const int byte = row*256 + (((ks*32 + kg*8)*2) ^ ((row & 7) << 4));
            AH[ks] = *reinterpret_cast<const bf16x8*>(
                reinterpret_cast<const char*>(sHT) + byte);
            AV[ks] = *reinterpret_cast<const bf16x8*>(
                VRFb + (size_t)(nh*256 + row)*128 + ks*32 + kg*8);
        }
        f32x4 aTr = (f32x4)0.f, aTi = (f32x4)0.f;
        f32x4 aWr = (f32x4)0.f, aWi = (f32x4)0.f;
        f32x4 aVr = (f32x4)0.f, aVi = (f32x4)0.f;
#pragma unroll
        for (int ks = 0; ks < 4; ++ks) {
            aTr = MFMA16(AH[ks], BG[0][ks], aTr, 0, 0, 0);
            aTi = MFMA16(AH[ks], BG[1][ks], aTi, 0, 0, 0);
            aWr = MFMA16(AH[ks], BG[2][ks], aWr, 0, 0, 0);
            aWi = MFMA16(AH[ks], BG[3][ks], aWi, 0, 0, 0);
            aVr = MFMA16(AV[ks], BV[0][ks], aVr, 0, 0, 0);
            aVi = MFMA16(AV[ks], BV[1][ks], aVi, 0, 0, 0);
        }
        // epilogue: C/D layout col = lane&15 = d, row = kg*4+r = n-offset
        const int d = j;
#pragma unroll
        for (int r = 0; r < 4; ++r) {
            const int n = nh*256 + n0 + kg*4 + r;
            const size_t i0 = ((size_t)(k*2 + 0)*NN + n)*DD + d;
            const size_t i1 = ((size_t)(k*2 + 1)*NN + n)*DD + d;
            tempb[i0] = f2bf(aTr[r]); tempb[i1] = f2bf(aTi[r]);
            TWb[i0]   = f2bf(aWr[r]); TWb[i1]   = f2bf(aWi[r]);
            const float br_ = aWr[r] + 0.5f*(aVr[r]*irx - Y[i0]);
            const float bi_ = aWi[r] + 0.5f*(aVi[r]*irx - Y[i1]);
            Bb[i0] = f2bf(br_); Bb[i1] = f2bf(bi_);
        }
    }
}

// ---------------------------------------------------------------------------
// Kernel D: Epart[ks] = sum_{kappa slice} TW @ temp^H  (complex 512x512, MFMA)
// ---------------------------------------------------------------------------
__global__ __launch_bounds__(256) void egemm_kernel(
    const unsigned short* __restrict__ TWb, const unsigned short* __restrict__ tmpb,
    float* __restrict__ Epart)
{
    const int ib = blockIdx.x >> 3;
    const int ks = blockIdx.x & 7;
    const int jb = blockIdx.y;
    const int w    = threadIdx.x >> 6;
    const int lane = threadIdx.x & 63;
    const int m  = lane & 15;
    const int kg = lane >> 4;
    const int iw = ib*64 + (w>>1)*32;
    const int jw = jb*64 + (w&1)*32;
    const int d0  = (kg & 1) * 8;
    const int kof = kg >> 1;

    f32x4 RR[2][2], II[2][2], RI[2][2], IR[2][2];
#pragma unroll
    for (int is = 0; is < 2; ++is)
#pragma unroll
        for (int js = 0; js < 2; ++js) {
            RR[is][js] = (f32x4)0.f; II[is][js] = (f32x4)0.f;
            RI[is][js] = (f32x4)0.f; IR[is][js] = (f32x4)0.f;
        }

#pragma unroll 2
    for (int c = 0; c < 32; ++c) {
        const int chunk = ks*32 + c;
        const int kp = chunk*2 + kof;
        const unsigned short* Ab = TWb  + ((size_t)(kp*2+0)*NN + iw + m)*DD + d0;
        const unsigned short* Bb2 = tmpb + ((size_t)(kp*2+0)*NN + jw + m)*DD + d0;
        bf16x8 ar[2], ai[2], br[2], bi[2];
#pragma unroll
        for (int is = 0; is < 2; ++is) {
            ar[is] = *reinterpret_cast<const bf16x8*>(Ab + (size_t)is*16*DD);
            ai[is] = *reinterpret_cast<const bf16x8*>(Ab + (size_t)NN*DD + (size_t)is*16*DD);
        }
#pragma unroll
        for (int js = 0; js < 2; ++js) {
            br[js] = *reinterpret_cast<const bf16x8*>(Bb2 + (size_t)js*16*DD);
            bi[js] = *reinterpret_cast<const bf16x8*>(Bb2 + (size_t)NN*DD + (size_t)js*16*DD);
        }
#pragma unroll
        for (int is = 0; is < 2; ++is)
#pragma unroll
            for (int js = 0; js < 2; ++js) {
                RR[is][js] = MFMA16(ar[is], br[js], RR[is][js], 0, 0, 0);
                II[is][js] = MFMA16(ai[is], bi[js], II[is][js], 0, 0, 0);
                RI[is][js] = MFMA16(ar[is], bi[js], RI[is][js], 0, 0, 0);
                IR[is][js] = MFMA16(ai[is], br[js], IR[is][js], 0, 0, 0);
            }
    }

    float* Eb = Epart + (size_t)ks*2*NN*NN;
#pragma unroll
    for (int is = 0; is < 2; ++is)
#pragma unroll
        for (int js = 0; js < 2; ++js) {
            const int i = iw + is*16 + kg*4;
            const int jx = jw + js*16 + m;
#pragma unroll
            for (int r = 0; r < 4; ++r) {
                Eb[(size_t)(i+r)*NN + jx]               = RR[is][js][r] + II[is][js][r];
                Eb[(size_t)NN*NN + (size_t)(i+r)*NN + jx] = IR[is][js][r] - RI[is][js][r];
            }
        }
}

// ---------------------------------------------------------------------------
// Kernel E: M = (sum Epart)/c ; S0 = I - M ; S0T  (bf16)
// ---------------------------------------------------------------------------
__global__ __launch_bounds__(256) void reduceinit_kernel(
    const float* __restrict__ Epart,
    const float* __restrict__ rhoX, const float* __restrict__ mu,
    unsigned short* __restrict__ Mb, unsigned short* __restrict__ S0,
    unsigned short* __restrict__ S0T)
{
    const size_t idx = (size_t)blockIdx.x*256 + threadIdx.x;   // over 2*NN*NN
    const float ic = 1.f / (1.f/(2.f*rhoX[0]) + mu[0]);
    const size_t pl = (size_t)2*NN*NN;
    float s = 0.f;
#pragma unroll
    for (int ks = 0; ks < 8; ++ks) s += Epart[(size_t)ks*pl + idx];
    const float mm = s * ic;
    Mb[idx] = f2bf(mm);
    const int p = (int)(idx / ((size_t)NN*NN));
    const size_t rem = idx - (size_t)p*NN*NN;
    const int i = (int)(rem / NN), jx = (int)(rem % NN);
    const float s0 = ((p == 0 && i == jx) ? 1.f : 0.f) - mm;
    const unsigned short b = f2bf(s0);
    S0[idx] = b;
    S0T[(size_t)p*NN*NN + (size_t)jx*NN + i] = b;
}

// ---------------------------------------------------------------------------
// Kernel F: Sout = I - M @ Sin  (complex MFMA; also writes Sout^T)
// ---------------------------------------------------------------------------
__global__ __launch_bounds__(256) void cgemm_kernel(
    const unsigned short* __restrict__ Mb, const unsigned short* __restrict__ SinT,
    unsigned short* __restrict__ Sout, unsigned short* __restrict__ SoutT)
{
    const int w    = threadIdx.x >> 6;
    const int lane = threadIdx.x & 63;
    const int m  = lane & 15;
    const int kg = lane >> 4;
    const int i0 = blockIdx.y*32 + (w>>1)*16;
    const int j0 = blockIdx.x*32 + (w&1)*16;

    f32x4 RR = (f32x4)0.f, II = (f32x4)0.f, RI = (f32x4)0.f, IR = (f32x4)0.f;

#pragma unroll 4
    for (int c = 0; c < 16; ++c) {
        const int l0 = c*32 + kg*8;
        const bf16x8 ar = *reinterpret_cast<const bf16x8*>(Mb   + (size_t)(i0+m)*NN + l0);
        const bf16x8 ai = *reinterpret_cast<const bf16x8*>(Mb   + (size_t)NN*NN + (size_t)(i0+m)*NN + l0);
        const bf16x8 br = *reinterpret_cast<const bf16x8*>(SinT + (size_t)(j0+m)*NN + l0);
        const bf16x8 bi = *reinterpret_cast<const bf16x8*>(SinT + (size_t)NN*NN + (size_t)(j0+m)*NN + l0);
        RR = MFMA16(ar, br, RR, 0, 0, 0);
        II = MFMA16(ai, bi, II, 0, 0, 0);
        RI = MFMA16(ar, bi, RI, 0, 0, 0);
        IR = MFMA16(ai, br, IR, 0, 0, 0);
    }
#pragma unroll
    for (int r = 0; r < 4; ++r) {
        const int i = i0 + kg*4 + r;
        const int jx = j0 + m;
        const float sr = ((i == jx) ? 1.f : 0.f) - RR[r] + II[r];
        const float si = -(RI[r] + IR[r]);
        const unsigned short hr = f2bf(sr), hi = f2bf(si);
        Sout[(size_t)i*NN + jx] = hr;
        Sout[(size_t)NN*NN + (size_t)i*NN + jx] = hi;
        SoutT[(size_t)jx*NN + i] = hr;
        SoutT[(size_t)NN*NN + (size_t)jx*NN + i] = hi;
    }
}

// ---------------------------------------------------------------------------
// Kernel G: X[k] = (S @ B[k]) * ic + params4[k]  (MFMA; B transposed in LDS)
// ---------------------------------------------------------------------------
__global__ __launch_bounds__(256) void final_kernel(
    const unsigned short* __restrict__ Sb, const unsigned short* __restrict__ Bb,
    const float* __restrict__ par4,
    const float* __restrict__ rhoX, const float* __restrict__ mu,
    float* __restrict__ Xout)
{
    const int k = blockIdx.x;
    __shared__ __align__(16) unsigned short sBT[2][DD][520];

    {   // stage + transpose B[k] ([2][512][16] -> [2][16][512])
        const unsigned short* Bk = Bb + (size_t)k*2*NN*DD;
        for (int q = 0; q < 8; ++q) {
            const int t8 = q*256 + threadIdx.x;    // 0..2047
            const u16x8 v = *reinterpret_cast<const u16x8*>(Bk + (size_t)t8*8);
            const int flat = t8*8;
            const int p = flat >> 13, n = (flat >> 4) & 511, dd0 = flat & 15;
#pragma unroll
            for (int jj = 0; jj < 8; ++jj) sBT[p][dd0+jj][n] = v[jj];
        }
    }
    __syncthreads();

    const int w    = threadIdx.x >> 6;
    const int lane = threadIdx.x & 63;
    const int m  = lane & 15;
    const int kg = lane >> 4;
    const int i0 = blockIdx.y*64 + w*16;

    f32x4 RR = (f32x4)0.f, II = (f32x4)0.f, RI = (f32x4)0.f, IR = (f32x4)0.f;

#pragma unroll 4
    for (int c = 0; c < 16; ++c) {
        const int l0 = c*32 + kg*8;
        const bf16x8 ar = *reinterpret_cast<const bf16x8*>(Sb + (size_t)(i0+m)*NN + l0);
        const bf16x8 ai = *reinterpret_cast<const bf16x8*>(Sb + (size_t)NN*NN + (size_t)(i0+m)*NN + l0);
        const bf16x8 br = *reinterpret_cast<const bf16x8*>(&sBT[0][m][l0]);
        const bf16x8 bi = *reinterpret_cast<const bf16x8*>(&sBT[1][m][l0]);
        RR = MFMA16(ar, br, RR, 0, 0, 0);
        II = MFMA16(ai, bi, II, 0, 0, 0);
        RI = MFMA16(ar, bi, RI, 0, 0, 0);
        IR = MFMA16(ai, br, IR, 0, 0, 0);
    }
    const float ic = 1.f / (1.f/(2.f*rhoX[0]) + mu[0]);
#pragma unroll
    for (int r = 0; r < 4; ++r) {
        const int i = i0 + kg*4 + r;
        const int d = m;
        const size_t idx0 = ((size_t)(k*2+0)*NN + i)*DD + d;
        const size_t idx1 = ((size_t)(k*2+1)*NN + i)*DD + d;
        Xout[idx0] = (RR[r] - II[r])*ic + par4[idx0];
        Xout[idx1] = (RI[r] + IR[r])*ic + par4[idx1];
    }
}

// ---------------------------------------------------------------------------
extern "C" void kernel_launch(void* const* d_in, const int* in_sizes, int n_in,
                              void* d_out, int out_size, void* d_ws, size_t ws_size,
                              hipStream_t stream) {
    const float* H     = (const float*)d_in[0];
    const float* U_RF  = (const float*)d_in[1];
    const float* U_BB  = (const float*)d_in[2];
    const float* W     = (const float*)d_in[3];
    const float* V_RF  = (const float*)d_in[4];
    const float* V_BB  = (const float*)d_in[5];
    const float* Y     = (const float*)d_in[6];
    // d_in[7] = rho (unused by reference)
    const float* rhoX  = (const float*)d_in[8];
    const float* mu    = (const float*)d_in[9];
    const float* par4  = (const float*)d_in[10];
    float* Xout = (float*)d_out;

    unsigned short* u = (unsigned short*)d_ws;
    const size_t bigE = (size_t)KK*2*NN*DD;    // 8,388,608
    const size_t plE  = (size_t)2*NN*NN;       //   524,288
    unsigned short* tempb = u;
    unsigned short* TWb   = tempb + bigE;
    unsigned short* Bb    = TWb + bigE;
    unsigned short* GT2   = Bb + bigE;                         // 512*4*16*128
    unsigned short* VBT2  = GT2 + (size_t)KK*4*DD*128;         // 512*2*16*128
    unsigned short* VRFb  = VBT2 + (size_t)KK*2*DD*128;        // 512*128
    unsigned short* Mb    = VRFb + (size_t)NN*128;
    unsigned short* S0    = Mb + plE;
    unsigned short* S0T   = S0 + plE;
    unsigned short* S1    = S0T + plE;
    unsigned short* S1T   = S1 + plE;
    float* Epart = (float*)(S1T + plE);                        // 8*plE floats

    vrfb_kernel<<<256, 256, 0, stream>>>(V_RF, VRFb);
    small_kernel<<<KK, 256, 0, stream>>>(U_RF, U_BB, W, V_BB, GT2, VBT2);
    prep_main<<<dim3(KK, 2), 256, 0, stream>>>(H, GT2, VBT2, VRFb, Y, rhoX,
                                               tempb, TWb, Bb);
    egemm_kernel<<<dim3(64, 8), 256, 0, stream>>>(TWb, tempb, Epart);
    reduceinit_kernel<<<(int)(plE/256), 256, 0, stream>>>(Epart, rhoX, mu, Mb, S0, S0T);

    unsigned short* sin_  = S0; unsigned short* sinT_  = S0T;
    unsigned short* sout_ = S1; unsigned short* soutT_ = S1T;
    for (int it = 0; it < 7; ++it) {           // Neumann degree 8
        cgemm_kernel<<<dim3(16, 16), 256, 0, stream>>>(Mb, sinT_, sout_, soutT_);
        unsigned short* t1 = sin_;  sin_  = sout_;  sout_  = t1;
        unsigned short* t2 = sinT_; sinT_ = soutT_; soutT_ = t2;
    }
    final_kernel<<<dim3(KK, 8), 256, 0, stream>>>(sin_, Bb, par4, rhoX, mu, Xout);
}